// Round 1
// baseline (624.821 us; speedup 1.0000x reference)
//
#include <hip/hip_runtime.h>

// Problem constants
constexpr int NB = 8, NH = 8, NN = 1024, DK = 64, ED = 16;
constexpr long QSZ = (long)NB * NH * NN * DK;       // 4,194,304
constexpr long BIAS_SZ = (long)NB * NN * NN;        // 8,388,608

typedef _Float16 h8 __attribute__((ext_vector_type(8)));
typedef _Float16 h4 __attribute__((ext_vector_type(4)));
typedef float f4 __attribute__((ext_vector_type(4)));

// ws layout (bytes)
constexpr size_t OFF_QH = 0;                         // 8 MiB fp16
constexpr size_t OFF_KH = 8388608;                   // 8 MiB fp16
constexpr size_t OFF_VT = 16777216;                  // 8 MiB fp16 (transposed [bh][d][k])
constexpr size_t OFF_BIAS = 25165824;                // 32 MiB fp32
constexpr size_t OFF_FLAG = 58720256;                // 4 B
constexpr size_t WS_NEED = OFF_FLAG + 4;

static __device__ __forceinline__ float tanh_fast(float x) {
  x = fminf(15.f, fmaxf(-15.f, x));
  float e = __expf(2.f * x);
  return __fdividef(e - 1.f, e + 1.f);   // (e^2x-1)/(e^2x+1), NaN-free after clamp
}

// ---------- prep: Q (x0.125) and K -> fp16, same layout ----------
__global__ __launch_bounds__(256) void k_prep_qk(
    const float* __restrict__ Q, const float* __restrict__ K,
    _Float16* __restrict__ Qh, _Float16* __restrict__ Kh) {
  int i = blockIdx.x * 256 + threadIdx.x;
  const int n4 = (int)(QSZ / 4);
  if (i < n4) {
    float4 v = reinterpret_cast<const float4*>(Q)[i];
    h4 o; o[0] = (_Float16)(v.x * 0.125f); o[1] = (_Float16)(v.y * 0.125f);
          o[2] = (_Float16)(v.z * 0.125f); o[3] = (_Float16)(v.w * 0.125f);
    reinterpret_cast<h4*>(Qh)[i] = o;
  } else {
    int j = i - n4;
    float4 v = reinterpret_cast<const float4*>(K)[j];
    h4 o; o[0] = (_Float16)v.x; o[1] = (_Float16)v.y;
          o[2] = (_Float16)v.z; o[3] = (_Float16)v.w;
    reinterpret_cast<h4*>(Kh)[j] = o;
  }
}

// ---------- prep: V [bh][k][d] fp32 -> Vt [bh][d][k] fp16 ----------
// one wave per (bh, 16-k chunk); lane owns column d; reads coalesced, writes 32B/lane
__global__ __launch_bounds__(256) void k_prep_vt(
    const float* __restrict__ V, _Float16* __restrict__ Vt) {
  int wid = (blockIdx.x * 256 + threadIdx.x) >> 6;   // 4096 waves
  int lane = threadIdx.x & 63;
  int bh = wid >> 6;
  int k0 = (wid & 63) << 4;
  const float* Vb = V + (long)bh * NN * DK;
  _Float16* Vo = Vt + (long)bh * DK * NN + (long)lane * NN + k0;
  h8 p0, p1;
#pragma unroll
  for (int i = 0; i < 16; ++i) {
    float v = Vb[(long)(k0 + i) * DK + lane];
    if (i < 8) p0[i] = (_Float16)v; else p1[i - 8] = (_Float16)v;
  }
  *reinterpret_cast<h8*>(Vo) = p0;
  *reinterpret_cast<h8*>(Vo + 8) = p1;
}

// ---------- detect mask element width (bool bytes vs int32) ----------
__global__ void k_detect(const unsigned char* __restrict__ m, int* __restrict__ flag) {
  int t = threadIdx.x;
  int any = 0;
  for (int i = t; i < 4096; i += 256)
    if ((i & 3) && m[i]) any = 1;          // int32 0/1 never has nonzero at %4!=0
  unsigned long long b = __ballot(any);
  if ((t & 63) == 0 && b) atomicOr(flag, 1);
}

// ---------- edge-bias MLP + mask fold: biasM[b][q][k] ----------
// grid = (b*NN + q) = 8192 blocks; wave w covers k in [w*256, w*256+256)
__global__ __launch_bounds__(256) void k_bias(
    const float* __restrict__ edge, const void* __restrict__ maskp,
    const float* __restrict__ W1, const float* __restrict__ b1,
    const float* __restrict__ W2, const float* __restrict__ b2,
    const int* __restrict__ flag, float* __restrict__ biasM) {
  int bq = blockIdx.x;
  int w = threadIdx.x >> 6, l = threadIdx.x & 63;
  int g = l >> 4, s = l & 15;
  bool isbool = (*flag != 0);
  // B-frags of W1 (K padded 16->32 with zeros): lane holds W1[8g+j][ct*16+s]
  h8 bw0, bw1, bw2, bw3;
#pragma unroll
  for (int j = 0; j < 8; ++j) {
    int kk = 8 * g + j;
    bool ok = kk < ED;
    bw0[j] = ok ? (_Float16)W1[kk * 64 + 0  + s] : (_Float16)0.f;
    bw1[j] = ok ? (_Float16)W1[kk * 64 + 16 + s] : (_Float16)0.f;
    bw2[j] = ok ? (_Float16)W1[kk * 64 + 32 + s] : (_Float16)0.f;
    bw3[j] = ok ? (_Float16)W1[kk * 64 + 48 + s] : (_Float16)0.f;
  }
  float b1v0 = b1[s], b1v1 = b1[16 + s], b1v2 = b1[32 + s], b1v3 = b1[48 + s];
  float w2v0 = W2[s], w2v1 = W2[16 + s], w2v2 = W2[32 + s], w2v3 = W2[48 + s];
  float b2v = b2[0];
  const float* erow = edge + (long)bq * NN * ED;
  float* orow = biasM + (long)bq * NN;
  const int* mrowi = (const int*)maskp + (long)bq * NN;
  const unsigned char* mrowb = (const unsigned char*)maskp + (long)bq * NN;

  for (int cc = 0; cc < 16; ++cc) {
    int k0 = w * 256 + cc * 16;
    // A-frag: row = pair s, k = 8g+j ; only groups 0,1 hold real data (ED=16)
    h8 af = {0, 0, 0, 0, 0, 0, 0, 0};
    if (g < 2) {
      const float4* ep = reinterpret_cast<const float4*>(erow + (long)(k0 + s) * ED + 8 * g);
      float4 e0 = ep[0], e1 = ep[1];
      af[0] = (_Float16)e0.x; af[1] = (_Float16)e0.y; af[2] = (_Float16)e0.z; af[3] = (_Float16)e0.w;
      af[4] = (_Float16)e1.x; af[5] = (_Float16)e1.y; af[6] = (_Float16)e1.z; af[7] = (_Float16)e1.w;
    }
    f4 z = {0.f, 0.f, 0.f, 0.f};
    f4 hp0 = __builtin_amdgcn_mfma_f32_16x16x32_f16(af, bw0, z, 0, 0, 0);
    f4 hp1 = __builtin_amdgcn_mfma_f32_16x16x32_f16(af, bw1, z, 0, 0, 0);
    f4 hp2 = __builtin_amdgcn_mfma_f32_16x16x32_f16(af, bw2, z, 0, 0, 0);
    f4 hp3 = __builtin_amdgcn_mfma_f32_16x16x32_f16(af, bw3, z, 0, 0, 0);
    float part0, part1, part2, part3;
#pragma unroll
    for (int j = 0; j < 4; ++j) {
      float a = tanh_fast(hp0[j] + b1v0) * w2v0;
      a += tanh_fast(hp1[j] + b1v1) * w2v1;
      a += tanh_fast(hp2[j] + b1v2) * w2v2;
      a += tanh_fast(hp3[j] + b1v3) * w2v3;
      if (j == 0) part0 = a; else if (j == 1) part1 = a; else if (j == 2) part2 = a; else part3 = a;
    }
#pragma unroll
    for (int m = 1; m < 16; m <<= 1) {
      part0 += __shfl_xor(part0, m, 64);
      part1 += __shfl_xor(part1, m, 64);
      part2 += __shfl_xor(part2, m, 64);
      part3 += __shfl_xor(part3, m, 64);
    }
    if (s == 0) {   // lane 16g stores pairs k0+4g..+3
      int kp = k0 + 4 * g;
      int m0, m1, m2, m3;
      if (isbool) {
        uchar4 mk = *reinterpret_cast<const uchar4*>(mrowb + kp);
        m0 = mk.x; m1 = mk.y; m2 = mk.z; m3 = mk.w;
      } else {
        int4 mk = *reinterpret_cast<const int4*>(mrowi + kp);
        m0 = mk.x; m1 = mk.y; m2 = mk.z; m3 = mk.w;
      }
      float4 o;
      o.x = m0 ? -1e9f : part0 + b2v;
      o.y = m1 ? -1e9f : part1 + b2v;
      o.z = m2 ? -1e9f : part2 + b2v;
      o.w = m3 ? -1e9f : part3 + b2v;
      *reinterpret_cast<float4*>(orow + kp) = o;
    }
  }
}

// ---------- fused attention: S = Qh*Kh + biasM ; softmax (no max-sub) ; PV ----------
// grid = bh*16 + qblock (1024 blocks); wave w owns 16 q-rows
__global__ __launch_bounds__(256) void k_attn(
    const _Float16* __restrict__ Qh, const _Float16* __restrict__ Kh,
    const _Float16* __restrict__ Vt, const float* __restrict__ biasM,
    float* __restrict__ ctx, float* __restrict__ attn) {
  int bid = blockIdx.x;
  int bh = bid >> 4, qb = bid & 15;
  int b = bh >> 3;
  int w = threadIdx.x >> 6, l = threadIdx.x & 63;
  int g = l >> 4, s = l & 15;
  int q0 = qb * 64 + w * 16;
  const _Float16* Qw = Qh + ((long)bh * NN + q0) * DK;
  const _Float16* Kb = Kh + (long)bh * NN * DK;
  const _Float16* Vb = Vt + (long)bh * DK * NN;
  const float* bias0 = biasM + (long)b * NN * NN + (long)q0 * NN;
  h8 aQ0 = *reinterpret_cast<const h8*>(Qw + s * DK + 8 * g);
  h8 aQ1 = *reinterpret_cast<const h8*>(Qw + s * DK + 32 + 8 * g);
  const float* bl0 = bias0 + (long)(4 * g + 0) * NN + s;
  const float* bl1 = bias0 + (long)(4 * g + 1) * NN + s;
  const float* bl2 = bias0 + (long)(4 * g + 2) * NN + s;
  const float* bl3 = bias0 + (long)(4 * g + 3) * NN + s;

  // pass 1: row sums of exp(S)
  float ls0 = 0.f, ls1 = 0.f, ls2 = 0.f, ls3 = 0.f;
  for (int c0 = 0; c0 < NN; c0 += 32) {
#pragma unroll
    for (int ct = 0; ct < 2; ++ct) {
      int kv = c0 + ct * 16;
      const _Float16* kp = Kb + (long)(kv + s) * DK + 8 * g;
      h8 bk0 = *reinterpret_cast<const h8*>(kp);
      h8 bk1 = *reinterpret_cast<const h8*>(kp + 32);
      f4 acc = {0.f, 0.f, 0.f, 0.f};
      acc = __builtin_amdgcn_mfma_f32_16x16x32_f16(aQ0, bk0, acc, 0, 0, 0);
      acc = __builtin_amdgcn_mfma_f32_16x16x32_f16(aQ1, bk1, acc, 0, 0, 0);
      ls0 += __expf(acc[0] + bl0[kv]);
      ls1 += __expf(acc[1] + bl1[kv]);
      ls2 += __expf(acc[2] + bl2[kv]);
      ls3 += __expf(acc[3] + bl3[kv]);
    }
  }
#pragma unroll
  for (int m = 1; m < 16; m <<= 1) {
    ls0 += __shfl_xor(ls0, m, 64);
    ls1 += __shfl_xor(ls1, m, 64);
    ls2 += __shfl_xor(ls2, m, 64);
    ls3 += __shfl_xor(ls3, m, 64);
  }
  float iv0 = __fdividef(1.f, ls0), iv1 = __fdividef(1.f, ls1);
  float iv2 = __fdividef(1.f, ls2), iv3 = __fdividef(1.f, ls3);

  // pass 2: recompute S, write attn, accumulate PV
  __shared__ _Float16 plds[4][16][40];   // per-wave P chunk [16 q][32 kv], pitch 40
  f4 ca0 = {0.f,0.f,0.f,0.f}, ca1 = {0.f,0.f,0.f,0.f};
  f4 ca2 = {0.f,0.f,0.f,0.f}, ca3 = {0.f,0.f,0.f,0.f};
  float* attnw = attn + ((long)bh * NN + q0) * NN;
  for (int c0 = 0; c0 < NN; c0 += 32) {
#pragma unroll
    for (int ct = 0; ct < 2; ++ct) {
      int kv = c0 + ct * 16;
      const _Float16* kp = Kb + (long)(kv + s) * DK + 8 * g;
      h8 bk0 = *reinterpret_cast<const h8*>(kp);
      h8 bk1 = *reinterpret_cast<const h8*>(kp + 32);
      f4 acc = {0.f, 0.f, 0.f, 0.f};
      acc = __builtin_amdgcn_mfma_f32_16x16x32_f16(aQ0, bk0, acc, 0, 0, 0);
      acc = __builtin_amdgcn_mfma_f32_16x16x32_f16(aQ1, bk1, acc, 0, 0, 0);
      float p0 = __expf(acc[0] + bl0[kv]) * iv0;
      float p1 = __expf(acc[1] + bl1[kv]) * iv1;
      float p2 = __expf(acc[2] + bl2[kv]) * iv2;
      float p3 = __expf(acc[3] + bl3[kv]) * iv3;
      attnw[(4 * g + 0) * NN + kv + s] = p0;
      attnw[(4 * g + 1) * NN + kv + s] = p1;
      attnw[(4 * g + 2) * NN + kv + s] = p2;
      attnw[(4 * g + 3) * NN + kv + s] = p3;
      plds[w][4 * g + 0][ct * 16 + s] = (_Float16)p0;
      plds[w][4 * g + 1][ct * 16 + s] = (_Float16)p1;
      plds[w][4 * g + 2][ct * 16 + s] = (_Float16)p2;
      plds[w][4 * g + 3][ct * 16 + s] = (_Float16)p3;
    }
    // A-frag of P: lane holds row s, kv 8g..8g+7 (cross-lane via per-wave LDS)
    h8 aP = *reinterpret_cast<const h8*>(&plds[w][s][8 * g]);
    const _Float16* vp = Vb + (long)s * NN + c0 + 8 * g;
    h8 bv0 = *reinterpret_cast<const h8*>(vp);
    h8 bv1 = *reinterpret_cast<const h8*>(vp + 16 * NN);
    h8 bv2 = *reinterpret_cast<const h8*>(vp + 32 * NN);
    h8 bv3 = *reinterpret_cast<const h8*>(vp + 48 * NN);
    ca0 = __builtin_amdgcn_mfma_f32_16x16x32_f16(aP, bv0, ca0, 0, 0, 0);
    ca1 = __builtin_amdgcn_mfma_f32_16x16x32_f16(aP, bv1, ca1, 0, 0, 0);
    ca2 = __builtin_amdgcn_mfma_f32_16x16x32_f16(aP, bv2, ca2, 0, 0, 0);
    ca3 = __builtin_amdgcn_mfma_f32_16x16x32_f16(aP, bv3, ca3, 0, 0, 0);
  }
  float* cw = ctx + ((long)bh * NN + q0) * DK;
#pragma unroll
  for (int j = 0; j < 4; ++j) {
    cw[(4 * g + j) * DK + 0  + s] = ca0[j];
    cw[(4 * g + j) * DK + 16 + s] = ca1[j];
    cw[(4 * g + j) * DK + 32 + s] = ca2[j];
    cw[(4 * g + j) * DK + 48 + s] = ca3[j];
  }
}

extern "C" void kernel_launch(void* const* d_in, const int* in_sizes, int n_in,
                              void* d_out, int out_size, void* d_ws, size_t ws_size,
                              hipStream_t stream) {
  const float* Q = (const float*)d_in[0];
  const float* K = (const float*)d_in[1];
  const float* V = (const float*)d_in[2];
  const void* mask = d_in[3];
  const float* edge = (const float*)d_in[4];
  const float* W1 = (const float*)d_in[5];
  const float* b1 = (const float*)d_in[6];
  const float* W2 = (const float*)d_in[7];
  const float* b2 = (const float*)d_in[8];
  float* ctx = (float*)d_out;
  float* attn = ctx + QSZ;                  // outputs: context then attn
  char* ws = (char*)d_ws;
  if (ws_size < WS_NEED) return;            // loud failure instead of corruption
  _Float16* Qh = (_Float16*)(ws + OFF_QH);
  _Float16* Kh = (_Float16*)(ws + OFF_KH);
  _Float16* Vt = (_Float16*)(ws + OFF_VT);
  float* biasM = (float*)(ws + OFF_BIAS);
  int* flag = (int*)(ws + OFF_FLAG);

  hipMemsetAsync(flag, 0, 4, stream);
  k_detect<<<1, 256, 0, stream>>>((const unsigned char*)mask, flag);
  k_prep_qk<<<8192, 256, 0, stream>>>(Q, K, Qh, Kh);
  k_prep_vt<<<1024, 256, 0, stream>>>(V, Vt);
  k_bias<<<8192, 256, 0, stream>>>(edge, mask, W1, b1, W2, b2, flag, biasM);
  k_attn<<<1024, 256, 0, stream>>>(Qh, Kh, Vt, biasM, ctx, attn);
}

// Round 3
// 554.296 us; speedup vs baseline: 1.1272x; 1.1272x over previous
//
#include <hip/hip_runtime.h>

// Problem constants
constexpr int NB = 8, NH = 8, NN = 1024, DK = 64, ED = 16;
constexpr long QSZ = (long)NB * NH * NN * DK;       // 4,194,304

typedef _Float16 h8 __attribute__((ext_vector_type(8)));
typedef _Float16 h4 __attribute__((ext_vector_type(4)));
typedef _Float16 h2 __attribute__((ext_vector_type(2)));
typedef float f4 __attribute__((ext_vector_type(4)));

// ws layout (bytes)
constexpr size_t OFF_QH = 0;                         // 8 MiB fp16 (pre-scaled by 0.125*log2e)
constexpr size_t OFF_KH = 8388608;                   // 8 MiB fp16
constexpr size_t OFF_VT = 16777216;                  // 8 MiB fp16 (transposed [bh][d][k])
constexpr size_t OFF_BIAS = 25165824;                // 32 MiB fp32 (bias*log2e, masked=-1e9)
constexpr size_t OFF_FLAG = 58720256;                // 4 B
constexpr size_t WS_NEED = OFF_FLAG + 4;

constexpr float LG2E = 1.4426950408889634f;          // log2(e)
constexpr float C2 = 2.8853900817779268f;            // 2*log2(e)
constexpr float QS = 0.125f * LG2E;                  // fold 1/sqrt(dk) and log2e into Q

static __device__ __forceinline__ float fexp2(float x) {
  float r; asm("v_exp_f32 %0, %1" : "=v"(r) : "v"(x)); return r;
}
static __device__ __forceinline__ float frcp(float x) {
  float r; asm("v_rcp_f32 %0, %1" : "=v"(r) : "v"(x)); return r;
}
static __device__ __forceinline__ h2 pkrtz(float a, float b) {
  return __builtin_bit_cast(h2, __builtin_amdgcn_cvt_pkrtz(a, b));
}

// ---------- prep: Q (x 0.125*log2e) and K -> fp16, same layout ----------
__global__ __launch_bounds__(256) void k_prep_qk(
    const float* __restrict__ Q, const float* __restrict__ K,
    _Float16* __restrict__ Qh, _Float16* __restrict__ Kh) {
  int i = blockIdx.x * 256 + threadIdx.x;
  const int n4 = (int)(QSZ / 4);
  if (i < n4) {
    float4 v = reinterpret_cast<const float4*>(Q)[i];
    h4 o; o[0] = (_Float16)(v.x * QS); o[1] = (_Float16)(v.y * QS);
          o[2] = (_Float16)(v.z * QS); o[3] = (_Float16)(v.w * QS);
    reinterpret_cast<h4*>(Qh)[i] = o;
  } else {
    int j = i - n4;
    float4 v = reinterpret_cast<const float4*>(K)[j];
    h4 o; o[0] = (_Float16)v.x; o[1] = (_Float16)v.y;
          o[2] = (_Float16)v.z; o[3] = (_Float16)v.w;
    reinterpret_cast<h4*>(Kh)[j] = o;
  }
}

// ---------- prep: V [bh][k][d] fp32 -> Vt [bh][d][k] fp16 ----------
__global__ __launch_bounds__(256) void k_prep_vt(
    const float* __restrict__ V, _Float16* __restrict__ Vt) {
  int wid = (blockIdx.x * 256 + threadIdx.x) >> 6;   // 4096 waves
  int lane = threadIdx.x & 63;
  int bh = wid >> 6;
  int k0 = (wid & 63) << 4;
  const float* Vb = V + (long)bh * NN * DK;
  _Float16* Vo = Vt + (long)bh * DK * NN + (long)lane * NN + k0;
  h8 p0, p1;
#pragma unroll
  for (int i = 0; i < 16; ++i) {
    float v = Vb[(long)(k0 + i) * DK + lane];
    if (i < 8) p0[i] = (_Float16)v; else p1[i - 8] = (_Float16)v;
  }
  *reinterpret_cast<h8*>(Vo) = p0;
  *reinterpret_cast<h8*>(Vo + 8) = p1;
}

// ---------- detect mask element width (bool bytes vs int32) ----------
__global__ void k_detect(const unsigned char* __restrict__ m, int* __restrict__ flag) {
  int t = threadIdx.x;
  int any = 0;
  for (int i = t; i < 4096; i += 256)
    if ((i & 3) && m[i]) any = 1;          // int32 0/1 never has nonzero at %4!=0
  unsigned long long b = __ballot(any);
  if ((t & 63) == 0 && b) atomicOr(flag, 1);
}

// ---------- edge-bias MLP + mask fold: biasM[b][q][k] = bias*log2e (or -1e9) ----------
// tanh(h) = 1 - 2*rcp(1+exp2(C2*h)); C2 folded into W1/b1; b1 enters as MFMA C-in.
// W2 dot: bias = sumW2 + b2 - 2 * sum_d W2[d]*r_d  -> accumulate w2*r only.
__global__ __launch_bounds__(256) void k_bias(
    const float* __restrict__ edge, const void* __restrict__ maskp,
    const float* __restrict__ W1, const float* __restrict__ b1,
    const float* __restrict__ W2, const float* __restrict__ b2,
    const int* __restrict__ flag, float* __restrict__ biasM) {
  int bq = blockIdx.x;
  int w = threadIdx.x >> 6, l = threadIdx.x & 63;
  int g = l >> 4, s = l & 15;
  bool isbool = (*flag != 0);
  // B-frags of W1*C2 (K padded 16->32 with zeros): lane holds W1[8g+j][16t+s]*C2
  h8 bw0, bw1, bw2, bw3;
#pragma unroll
  for (int j = 0; j < 8; ++j) {
    int kk = 8 * g + j;
    bool ok = kk < ED;
    bw0[j] = ok ? (_Float16)(W1[kk * 64 + 0  + s] * C2) : (_Float16)0.f;
    bw1[j] = ok ? (_Float16)(W1[kk * 64 + 16 + s] * C2) : (_Float16)0.f;
    bw2[j] = ok ? (_Float16)(W1[kk * 64 + 32 + s] * C2) : (_Float16)0.f;
    bw3[j] = ok ? (_Float16)(W1[kk * 64 + 48 + s] * C2) : (_Float16)0.f;
  }
  float b10 = b1[s] * C2, b11 = b1[16 + s] * C2, b12 = b1[32 + s] * C2, b13 = b1[48 + s] * C2;
  f4 cb0 = {b10, b10, b10, b10}, cb1 = {b11, b11, b11, b11};
  f4 cb2 = {b12, b12, b12, b12}, cb3 = {b13, b13, b13, b13};
  float w2v0 = W2[s], w2v1 = W2[16 + s], w2v2 = W2[32 + s], w2v3 = W2[48 + s];
  // sumW2 over all 64 dims (reduce local 4-sum over the 16-lane group)
  float sw = w2v0 + w2v1 + w2v2 + w2v3;
#pragma unroll
  for (int m = 1; m < 16; m <<= 1) sw += __shfl_xor(sw, m, 64);
  float base = (sw + b2[0]) * LG2E;

  const float* erow = edge + (long)bq * NN * ED;
  float* orow = biasM + (long)bq * NN;
  const int* mrowi = (const int*)maskp + (long)bq * NN;
  const unsigned char* mrowb = (const unsigned char*)maskp + (long)bq * NN;
  int k0base = w * 256;

  // depth-1 software pipeline on the edge loads (g<2 lanes only; others stay 0)
  float4 eA = {0, 0, 0, 0}, eB = {0, 0, 0, 0}, nA = {0, 0, 0, 0}, nB = {0, 0, 0, 0};
  if (g < 2) {
    const float4* ep = reinterpret_cast<const float4*>(erow + (long)(k0base + s) * ED + 8 * g);
    eA = ep[0]; eB = ep[1];
  }
  for (int cc = 0; cc < 16; ++cc) {
    int k0 = k0base + cc * 16;
    if (g < 2 && cc < 15) {
      const float4* ep = reinterpret_cast<const float4*>(erow + (long)(k0 + 16 + s) * ED + 8 * g);
      nA = ep[0]; nB = ep[1];
    }
    union { h8 v; h2 p[4]; } u;
    u.p[0] = pkrtz(eA.x, eA.y); u.p[1] = pkrtz(eA.z, eA.w);
    u.p[2] = pkrtz(eB.x, eB.y); u.p[3] = pkrtz(eB.z, eB.w);
    h8 af = u.v;                               // zeros for g>=2 (K-pad)
    f4 hp0 = __builtin_amdgcn_mfma_f32_16x16x32_f16(af, bw0, cb0, 0, 0, 0);
    f4 hp1 = __builtin_amdgcn_mfma_f32_16x16x32_f16(af, bw1, cb1, 0, 0, 0);
    f4 hp2 = __builtin_amdgcn_mfma_f32_16x16x32_f16(af, bw2, cb2, 0, 0, 0);
    f4 hp3 = __builtin_amdgcn_mfma_f32_16x16x32_f16(af, bw3, cb3, 0, 0, 0);
    float part0, part1, part2, part3;
#pragma unroll
    for (int j = 0; j < 4; ++j) {
      float a;
      a = w2v0 * frcp(fexp2(hp0[j]) + 1.f);
      a = fmaf(w2v1, frcp(fexp2(hp1[j]) + 1.f), a);
      a = fmaf(w2v2, frcp(fexp2(hp2[j]) + 1.f), a);
      a = fmaf(w2v3, frcp(fexp2(hp3[j]) + 1.f), a);
      if (j == 0) part0 = a; else if (j == 1) part1 = a; else if (j == 2) part2 = a; else part3 = a;
    }
#pragma unroll
    for (int m = 1; m < 16; m <<= 1) {
      part0 += __shfl_xor(part0, m, 64);
      part1 += __shfl_xor(part1, m, 64);
      part2 += __shfl_xor(part2, m, 64);
      part3 += __shfl_xor(part3, m, 64);
    }
    if (s == 0) {   // lane 16g stores k0+4g .. k0+4g+3
      int kp = k0 + 4 * g;
      int m0, m1, m2, m3;
      if (isbool) {
        uchar4 mk = *reinterpret_cast<const uchar4*>(mrowb + kp);
        m0 = mk.x; m1 = mk.y; m2 = mk.z; m3 = mk.w;
      } else {
        int4 mk = *reinterpret_cast<const int4*>(mrowi + kp);
        m0 = mk.x; m1 = mk.y; m2 = mk.z; m3 = mk.w;
      }
      float4 o;
      o.x = m0 ? -1e9f : fmaf(-C2, part0, base);
      o.y = m1 ? -1e9f : fmaf(-C2, part1, base);
      o.z = m2 ? -1e9f : fmaf(-C2, part2, base);
      o.w = m3 ? -1e9f : fmaf(-C2, part3, base);
      *reinterpret_cast<float4*>(orow + kp) = o;
    }
    eA = nA; eB = nB;
  }
}

// ---------- fused attention: S' = Qh*Kh + biasM (base-2 domain) ; softmax ; PV ----------
__global__ __launch_bounds__(256) void k_attn(
    const _Float16* __restrict__ Qh, const _Float16* __restrict__ Kh,
    const _Float16* __restrict__ Vt, const float* __restrict__ biasM,
    float* __restrict__ ctx, float* __restrict__ attn) {
  int bid = blockIdx.x;
  int bh = bid >> 4, qb = bid & 15;
  int b = bh >> 3;
  int w = threadIdx.x >> 6, l = threadIdx.x & 63;
  int g = l >> 4, s = l & 15;
  int q0 = qb * 64 + w * 16;
  const _Float16* Qw = Qh + ((long)bh * NN + q0) * DK;
  const _Float16* Kb = Kh + (long)bh * NN * DK;
  const _Float16* Vb = Vt + (long)bh * DK * NN;
  const float* bias0 = biasM + (long)b * NN * NN + (long)q0 * NN;
  h8 aQ0 = *reinterpret_cast<const h8*>(Qw + s * DK + 8 * g);
  h8 aQ1 = *reinterpret_cast<const h8*>(Qw + s * DK + 32 + 8 * g);
  const float* bl0 = bias0 + (long)(4 * g + 0) * NN + s;
  const float* bl1 = bias0 + (long)(4 * g + 1) * NN + s;
  const float* bl2 = bias0 + (long)(4 * g + 2) * NN + s;
  const float* bl3 = bias0 + (long)(4 * g + 3) * NN + s;

  // pass 1: row sums of exp2(S')
  float ls0 = 0.f, ls1 = 0.f, ls2 = 0.f, ls3 = 0.f;
  for (int c0 = 0; c0 < NN; c0 += 32) {
#pragma unroll
    for (int ct = 0; ct < 2; ++ct) {
      int kv = c0 + ct * 16;
      const _Float16* kp = Kb + (long)(kv + s) * DK + 8 * g;
      h8 bk0 = *reinterpret_cast<const h8*>(kp);
      h8 bk1 = *reinterpret_cast<const h8*>(kp + 32);
      f4 acc = {0.f, 0.f, 0.f, 0.f};
      acc = __builtin_amdgcn_mfma_f32_16x16x32_f16(aQ0, bk0, acc, 0, 0, 0);
      acc = __builtin_amdgcn_mfma_f32_16x16x32_f16(aQ1, bk1, acc, 0, 0, 0);
      ls0 += fexp2(acc[0] + bl0[kv]);
      ls1 += fexp2(acc[1] + bl1[kv]);
      ls2 += fexp2(acc[2] + bl2[kv]);
      ls3 += fexp2(acc[3] + bl3[kv]);
    }
  }
#pragma unroll
  for (int m = 1; m < 16; m <<= 1) {
    ls0 += __shfl_xor(ls0, m, 64);
    ls1 += __shfl_xor(ls1, m, 64);
    ls2 += __shfl_xor(ls2, m, 64);
    ls3 += __shfl_xor(ls3, m, 64);
  }
  float iv0 = frcp(ls0), iv1 = frcp(ls1), iv2 = frcp(ls2), iv3 = frcp(ls3);

  // pass 2: recompute S', write attn, accumulate PV
  __shared__ _Float16 plds[4][16][40];   // per-wave P chunk [16 q][32 kv], pitch 40
  f4 ca0 = {0.f,0.f,0.f,0.f}, ca1 = {0.f,0.f,0.f,0.f};
  f4 ca2 = {0.f,0.f,0.f,0.f}, ca3 = {0.f,0.f,0.f,0.f};
  float* attnw = attn + ((long)bh * NN + q0) * NN;
  for (int c0 = 0; c0 < NN; c0 += 32) {
#pragma unroll
    for (int ct = 0; ct < 2; ++ct) {
      int kv = c0 + ct * 16;
      const _Float16* kp = Kb + (long)(kv + s) * DK + 8 * g;
      h8 bk0 = *reinterpret_cast<const h8*>(kp);
      h8 bk1 = *reinterpret_cast<const h8*>(kp + 32);
      f4 acc = {0.f, 0.f, 0.f, 0.f};
      acc = __builtin_amdgcn_mfma_f32_16x16x32_f16(aQ0, bk0, acc, 0, 0, 0);
      acc = __builtin_amdgcn_mfma_f32_16x16x32_f16(aQ1, bk1, acc, 0, 0, 0);
      float p0 = fexp2(acc[0] + bl0[kv]) * iv0;
      float p1 = fexp2(acc[1] + bl1[kv]) * iv1;
      float p2 = fexp2(acc[2] + bl2[kv]) * iv2;
      float p3 = fexp2(acc[3] + bl3[kv]) * iv3;
      attnw[(4 * g + 0) * NN + kv + s] = p0;
      attnw[(4 * g + 1) * NN + kv + s] = p1;
      attnw[(4 * g + 2) * NN + kv + s] = p2;
      attnw[(4 * g + 3) * NN + kv + s] = p3;
      plds[w][4 * g + 0][ct * 16 + s] = (_Float16)p0;
      plds[w][4 * g + 1][ct * 16 + s] = (_Float16)p1;
      plds[w][4 * g + 2][ct * 16 + s] = (_Float16)p2;
      plds[w][4 * g + 3][ct * 16 + s] = (_Float16)p3;
    }
    h8 aP = *reinterpret_cast<const h8*>(&plds[w][s][8 * g]);
    const _Float16* vp = Vb + (long)s * NN + c0 + 8 * g;
    h8 bv0 = *reinterpret_cast<const h8*>(vp);
    h8 bv1 = *reinterpret_cast<const h8*>(vp + 16 * NN);
    h8 bv2 = *reinterpret_cast<const h8*>(vp + 32 * NN);
    h8 bv3 = *reinterpret_cast<const h8*>(vp + 48 * NN);
    ca0 = __builtin_amdgcn_mfma_f32_16x16x32_f16(aP, bv0, ca0, 0, 0, 0);
    ca1 = __builtin_amdgcn_mfma_f32_16x16x32_f16(aP, bv1, ca1, 0, 0, 0);
    ca2 = __builtin_amdgcn_mfma_f32_16x16x32_f16(aP, bv2, ca2, 0, 0, 0);
    ca3 = __builtin_amdgcn_mfma_f32_16x16x32_f16(aP, bv3, ca3, 0, 0, 0);
  }
  float* cw = ctx + ((long)bh * NN + q0) * DK;
#pragma unroll
  for (int j = 0; j < 4; ++j) {
    cw[(4 * g + j) * DK + 0  + s] = ca0[j];
    cw[(4 * g + j) * DK + 16 + s] = ca1[j];
    cw[(4 * g + j) * DK + 32 + s] = ca2[j];
    cw[(4 * g + j) * DK + 48 + s] = ca3[j];
  }
}

extern "C" void kernel_launch(void* const* d_in, const int* in_sizes, int n_in,
                              void* d_out, int out_size, void* d_ws, size_t ws_size,
                              hipStream_t stream) {
  const float* Q = (const float*)d_in[0];
  const float* K = (const float*)d_in[1];
  const float* V = (const float*)d_in[2];
  const void* mask = d_in[3];
  const float* edge = (const float*)d_in[4];
  const float* W1 = (const float*)d_in[5];
  const float* b1 = (const float*)d_in[6];
  const float* W2 = (const float*)d_in[7];
  const float* b2 = (const float*)d_in[8];
  float* ctx = (float*)d_out;
  float* attn = ctx + QSZ;                  // outputs: context then attn
  char* ws = (char*)d_ws;
  if (ws_size < WS_NEED) return;
  _Float16* Qh = (_Float16*)(ws + OFF_QH);
  _Float16* Kh = (_Float16*)(ws + OFF_KH);
  _Float16* Vt = (_Float16*)(ws + OFF_VT);
  float* biasM = (float*)(ws + OFF_BIAS);
  int* flag = (int*)(ws + OFF_FLAG);

  (void)hipMemsetAsync(flag, 0, 4, stream);
  k_detect<<<1, 256, 0, stream>>>((const unsigned char*)mask, flag);
  k_prep_qk<<<8192, 256, 0, stream>>>(Q, K, Qh, Kh);
  k_prep_vt<<<1024, 256, 0, stream>>>(V, Vt);
  k_bias<<<8192, 256, 0, stream>>>(edge, mask, W1, b1, W2, b2, flag, biasM);
  k_attn<<<1024, 256, 0, stream>>>(Qh, Kh, Vt, biasM, ctx, attn);
}

// Round 4
// 547.177 us; speedup vs baseline: 1.1419x; 1.0130x over previous
//
#include <hip/hip_runtime.h>

// Problem constants
constexpr int NB = 8, NH = 8, NN = 1024, DK = 64, ED = 16;
constexpr long QSZ = (long)NB * NH * NN * DK;       // 4,194,304

typedef _Float16 h8 __attribute__((ext_vector_type(8)));
typedef _Float16 h4 __attribute__((ext_vector_type(4)));
typedef _Float16 h2 __attribute__((ext_vector_type(2)));
typedef float f4 __attribute__((ext_vector_type(4)));

// ws layout (bytes)
constexpr size_t OFF_QH = 0;                         // 8 MiB fp16 (pre-scaled by 0.125*log2e)
constexpr size_t OFF_KH = 8388608;                   // 8 MiB fp16
constexpr size_t OFF_VT = 16777216;                  // 8 MiB fp16 (transposed [bh][d][k])
constexpr size_t OFF_BIAS = 25165824;                // 32 MiB fp32 (bias*log2e, masked=-1e9)
constexpr size_t OFF_FLAG = 58720256;                // 4 B
constexpr size_t WS_NEED = OFF_FLAG + 4;

constexpr float LG2E = 1.4426950408889634f;          // log2(e)
constexpr float C2 = 2.8853900817779268f;            // 2*log2(e)
constexpr float QS = 0.125f * LG2E;                  // fold 1/sqrt(dk) and log2e into Q

static __device__ __forceinline__ float fexp2(float x) {
  float r; asm("v_exp_f32 %0, %1" : "=v"(r) : "v"(x)); return r;
}
static __device__ __forceinline__ float frcp(float x) {
  float r; asm("v_rcp_f32 %0, %1" : "=v"(r) : "v"(x)); return r;
}
static __device__ __forceinline__ h2 pkrtz(float a, float b) {
  return __builtin_bit_cast(h2, __builtin_amdgcn_cvt_pkrtz(a, b));
}

// ---------- prep: Q (x 0.125*log2e) and K -> fp16, same layout ----------
__global__ __launch_bounds__(256) void k_prep_qk(
    const float* __restrict__ Q, const float* __restrict__ K,
    _Float16* __restrict__ Qh, _Float16* __restrict__ Kh) {
  int i = blockIdx.x * 256 + threadIdx.x;
  const int n4 = (int)(QSZ / 4);
  if (i < n4) {
    float4 v = reinterpret_cast<const float4*>(Q)[i];
    h4 o; o[0] = (_Float16)(v.x * QS); o[1] = (_Float16)(v.y * QS);
          o[2] = (_Float16)(v.z * QS); o[3] = (_Float16)(v.w * QS);
    reinterpret_cast<h4*>(Qh)[i] = o;
  } else {
    int j = i - n4;
    float4 v = reinterpret_cast<const float4*>(K)[j];
    h4 o; o[0] = (_Float16)v.x; o[1] = (_Float16)v.y;
          o[2] = (_Float16)v.z; o[3] = (_Float16)v.w;
    reinterpret_cast<h4*>(Kh)[j] = o;
  }
}

// ---------- prep: V [bh][k][d] fp32 -> Vt [bh][d][k] fp16 ----------
__global__ __launch_bounds__(256) void k_prep_vt(
    const float* __restrict__ V, _Float16* __restrict__ Vt) {
  int wid = (blockIdx.x * 256 + threadIdx.x) >> 6;   // 4096 waves
  int lane = threadIdx.x & 63;
  int bh = wid >> 6;
  int k0 = (wid & 63) << 4;
  const float* Vb = V + (long)bh * NN * DK;
  _Float16* Vo = Vt + (long)bh * DK * NN + (long)lane * NN + k0;
  h8 p0, p1;
#pragma unroll
  for (int i = 0; i < 16; ++i) {
    float v = Vb[(long)(k0 + i) * DK + lane];
    if (i < 8) p0[i] = (_Float16)v; else p1[i - 8] = (_Float16)v;
  }
  *reinterpret_cast<h8*>(Vo) = p0;
  *reinterpret_cast<h8*>(Vo + 8) = p1;
}

// ---------- detect mask element width (bool bytes vs int32) ----------
__global__ void k_detect(const unsigned char* __restrict__ m, int* __restrict__ flag) {
  int t = threadIdx.x;
  int any = 0;
  for (int i = t; i < 4096; i += 256)
    if ((i & 3) && m[i]) any = 1;          // int32 0/1 never has nonzero at %4!=0
  unsigned long long b = __ballot(any);
  if ((t & 63) == 0 && b) atomicOr(flag, 1);
}

// ---------- edge-bias MLP + mask fold: biasM[b][q][k] = bias*log2e (or -1e9) ----------
// Operand-swapped MFMA: D = W1^T_frag (A) x edge_frag (B) -> H^T[d][k]:
// lane l&15 = k (output col), (l>>4)*4+j = d_local. The W2-dot over d is then
// 16 in-register FMAs + 2 shfl_xor (16,32) instead of a 4-deep 16-shuffle tree.
// tanh(h) = 1 - 2*rcp(1+exp2(C2*h)); C2 folded into W1/b1; b1 enters as MFMA C-in.
__global__ __launch_bounds__(256) void k_bias(
    const float* __restrict__ edge, const void* __restrict__ maskp,
    const float* __restrict__ W1, const float* __restrict__ b1,
    const float* __restrict__ W2, const float* __restrict__ b2,
    const int* __restrict__ flag, float* __restrict__ biasM) {
  int bq = blockIdx.x;
  int w = threadIdx.x >> 6, l = threadIdx.x & 63;
  int g = l >> 4, s = l & 15;
  bool isbool = (*flag != 0);
  // W1*C2 fragments (K=ED padded 16->32 with zeros): lane l, elem j holds
  // W1[8g+j][16c+s]*C2. As the A operand the HW reads this as A[s][8g+j] =
  // W1^T chunk, exactly the transpose we need.
  h8 bw0, bw1, bw2, bw3;
#pragma unroll
  for (int j = 0; j < 8; ++j) {
    int kk = 8 * g + j;
    bool ok = kk < ED;
    bw0[j] = ok ? (_Float16)(W1[kk * 64 + 0  + s] * C2) : (_Float16)0.f;
    bw1[j] = ok ? (_Float16)(W1[kk * 64 + 16 + s] * C2) : (_Float16)0.f;
    bw2[j] = ok ? (_Float16)(W1[kk * 64 + 32 + s] * C2) : (_Float16)0.f;
    bw3[j] = ok ? (_Float16)(W1[kk * 64 + 48 + s] * C2) : (_Float16)0.f;
  }
  // C-in: b1[d]*C2 at D-row d_local = 4g+j ; per-chunk vectors
  f4 cb0, cb1, cb2, cb3;
  float w20[4], w21[4], w22[4], w23[4];
#pragma unroll
  for (int j = 0; j < 4; ++j) {
    int dl = 4 * g + j;
    cb0[j] = b1[0  + dl] * C2; w20[j] = W2[0  + dl];
    cb1[j] = b1[16 + dl] * C2; w21[j] = W2[16 + dl];
    cb2[j] = b1[32 + dl] * C2; w22[j] = W2[32 + dl];
    cb3[j] = b1[48 + dl] * C2; w23[j] = W2[48 + dl];
  }
  // sum of all W2 (for base): per-lane partial over held dims, reduce over g
  float sw = 0.f;
#pragma unroll
  for (int j = 0; j < 4; ++j) sw += w20[j] + w21[j] + w22[j] + w23[j];
  sw += __shfl_xor(sw, 16, 64);
  sw += __shfl_xor(sw, 32, 64);
  float base = (sw + b2[0]) * LG2E;

  const float* erow = edge + (long)bq * NN * ED;
  float* orow = biasM + (long)bq * NN;
  const int* mrowi = (const int*)maskp + (long)bq * NN;
  const unsigned char* mrowb = (const unsigned char*)maskp + (long)bq * NN;
  int k0base = w * 256;

  // depth-1 software pipeline on the edge loads (g<2 lanes only; others stay 0)
  float4 eA = {0, 0, 0, 0}, eB = {0, 0, 0, 0}, nA = {0, 0, 0, 0}, nB = {0, 0, 0, 0};
  if (g < 2) {
    const float4* ep = reinterpret_cast<const float4*>(erow + (long)(k0base + s) * ED + 8 * g);
    eA = ep[0]; eB = ep[1];
  }
  for (int cc = 0; cc < 16; ++cc) {
    int k0 = k0base + cc * 16;
    if (g < 2 && cc < 15) {
      const float4* ep = reinterpret_cast<const float4*>(erow + (long)(k0 + 16 + s) * ED + 8 * g);
      nA = ep[0]; nB = ep[1];
    }
    union { h8 v; h2 p[4]; } u;
    u.p[0] = pkrtz(eA.x, eA.y); u.p[1] = pkrtz(eA.z, eA.w);
    u.p[2] = pkrtz(eB.x, eB.y); u.p[3] = pkrtz(eB.z, eB.w);
    h8 af = u.v;                               // zeros for g>=2 (K-pad)
    // D[d_local][k]: row = 4g+j (hidden dim), col lane = k
    f4 hp0 = __builtin_amdgcn_mfma_f32_16x16x32_f16(bw0, af, cb0, 0, 0, 0);
    f4 hp1 = __builtin_amdgcn_mfma_f32_16x16x32_f16(bw1, af, cb1, 0, 0, 0);
    f4 hp2 = __builtin_amdgcn_mfma_f32_16x16x32_f16(bw2, af, cb2, 0, 0, 0);
    f4 hp3 = __builtin_amdgcn_mfma_f32_16x16x32_f16(bw3, af, cb3, 0, 0, 0);
    float p0 = 0.f, p1 = 0.f, p2 = 0.f, p3 = 0.f;
#pragma unroll
    for (int j = 0; j < 4; ++j) {
      p0 = fmaf(w20[j], frcp(fexp2(hp0[j]) + 1.f), p0);
      p1 = fmaf(w21[j], frcp(fexp2(hp1[j]) + 1.f), p1);
      p2 = fmaf(w22[j], frcp(fexp2(hp2[j]) + 1.f), p2);
      p3 = fmaf(w23[j], frcp(fexp2(hp3[j]) + 1.f), p3);
    }
    float part = (p0 + p1) + (p2 + p3);
    part += __shfl_xor(part, 16, 64);
    part += __shfl_xor(part, 32, 64);
    if (g == 0) {   // 16 lanes store bias[k0+s]: one coalesced 64B line
      int m = isbool ? (int)mrowb[k0 + s] : mrowi[k0 + s];
      orow[k0 + s] = m ? -1e9f : fmaf(-C2, part, base);
    }
    eA = nA; eB = nB;
  }
}

// ---------- fused attention: S' = Qh*Kh + biasM (base-2 domain) ; softmax ; PV ----------
__global__ __launch_bounds__(256) void k_attn(
    const _Float16* __restrict__ Qh, const _Float16* __restrict__ Kh,
    const _Float16* __restrict__ Vt, const float* __restrict__ biasM,
    float* __restrict__ ctx, float* __restrict__ attn) {
  int bid = blockIdx.x;
  int bh = bid >> 4, qb = bid & 15;
  int b = bh >> 3;
  int w = threadIdx.x >> 6, l = threadIdx.x & 63;
  int g = l >> 4, s = l & 15;
  int q0 = qb * 64 + w * 16;
  const _Float16* Qw = Qh + ((long)bh * NN + q0) * DK;
  const _Float16* Kb = Kh + (long)bh * NN * DK;
  const _Float16* Vb = Vt + (long)bh * DK * NN;
  const float* bias0 = biasM + (long)b * NN * NN + (long)q0 * NN;
  h8 aQ0 = *reinterpret_cast<const h8*>(Qw + s * DK + 8 * g);
  h8 aQ1 = *reinterpret_cast<const h8*>(Qw + s * DK + 32 + 8 * g);
  const float* bl0 = bias0 + (long)(4 * g + 0) * NN + s;
  const float* bl1 = bias0 + (long)(4 * g + 1) * NN + s;
  const float* bl2 = bias0 + (long)(4 * g + 2) * NN + s;
  const float* bl3 = bias0 + (long)(4 * g + 3) * NN + s;

  // pass 1: row sums of exp2(S')
  float ls0 = 0.f, ls1 = 0.f, ls2 = 0.f, ls3 = 0.f;
  for (int c0 = 0; c0 < NN; c0 += 32) {
#pragma unroll
    for (int ct = 0; ct < 2; ++ct) {
      int kv = c0 + ct * 16;
      const _Float16* kp = Kb + (long)(kv + s) * DK + 8 * g;
      h8 bk0 = *reinterpret_cast<const h8*>(kp);
      h8 bk1 = *reinterpret_cast<const h8*>(kp + 32);
      f4 acc = {0.f, 0.f, 0.f, 0.f};
      acc = __builtin_amdgcn_mfma_f32_16x16x32_f16(aQ0, bk0, acc, 0, 0, 0);
      acc = __builtin_amdgcn_mfma_f32_16x16x32_f16(aQ1, bk1, acc, 0, 0, 0);
      ls0 += fexp2(acc[0] + bl0[kv]);
      ls1 += fexp2(acc[1] + bl1[kv]);
      ls2 += fexp2(acc[2] + bl2[kv]);
      ls3 += fexp2(acc[3] + bl3[kv]);
    }
  }
#pragma unroll
  for (int m = 1; m < 16; m <<= 1) {
    ls0 += __shfl_xor(ls0, m, 64);
    ls1 += __shfl_xor(ls1, m, 64);
    ls2 += __shfl_xor(ls2, m, 64);
    ls3 += __shfl_xor(ls3, m, 64);
  }
  float iv0 = frcp(ls0), iv1 = frcp(ls1), iv2 = frcp(ls2), iv3 = frcp(ls3);

  // pass 2: recompute S', write attn, accumulate PV
  __shared__ _Float16 plds[4][16][40];   // per-wave P chunk [16 q][32 kv], pitch 40
  f4 ca0 = {0.f,0.f,0.f,0.f}, ca1 = {0.f,0.f,0.f,0.f};
  f4 ca2 = {0.f,0.f,0.f,0.f}, ca3 = {0.f,0.f,0.f,0.f};
  float* attnw = attn + ((long)bh * NN + q0) * NN;
  for (int c0 = 0; c0 < NN; c0 += 32) {
#pragma unroll
    for (int ct = 0; ct < 2; ++ct) {
      int kv = c0 + ct * 16;
      const _Float16* kp = Kb + (long)(kv + s) * DK + 8 * g;
      h8 bk0 = *reinterpret_cast<const h8*>(kp);
      h8 bk1 = *reinterpret_cast<const h8*>(kp + 32);
      f4 acc = {0.f, 0.f, 0.f, 0.f};
      acc = __builtin_amdgcn_mfma_f32_16x16x32_f16(aQ0, bk0, acc, 0, 0, 0);
      acc = __builtin_amdgcn_mfma_f32_16x16x32_f16(aQ1, bk1, acc, 0, 0, 0);
      float p0 = fexp2(acc[0] + bl0[kv]) * iv0;
      float p1 = fexp2(acc[1] + bl1[kv]) * iv1;
      float p2 = fexp2(acc[2] + bl2[kv]) * iv2;
      float p3 = fexp2(acc[3] + bl3[kv]) * iv3;
      attnw[(4 * g + 0) * NN + kv + s] = p0;
      attnw[(4 * g + 1) * NN + kv + s] = p1;
      attnw[(4 * g + 2) * NN + kv + s] = p2;
      attnw[(4 * g + 3) * NN + kv + s] = p3;
      plds[w][4 * g + 0][ct * 16 + s] = (_Float16)p0;
      plds[w][4 * g + 1][ct * 16 + s] = (_Float16)p1;
      plds[w][4 * g + 2][ct * 16 + s] = (_Float16)p2;
      plds[w][4 * g + 3][ct * 16 + s] = (_Float16)p3;
    }
    h8 aP = *reinterpret_cast<const h8*>(&plds[w][s][8 * g]);
    const _Float16* vp = Vb + (long)s * NN + c0 + 8 * g;
    h8 bv0 = *reinterpret_cast<const h8*>(vp);
    h8 bv1 = *reinterpret_cast<const h8*>(vp + 16 * NN);
    h8 bv2 = *reinterpret_cast<const h8*>(vp + 32 * NN);
    h8 bv3 = *reinterpret_cast<const h8*>(vp + 48 * NN);
    ca0 = __builtin_amdgcn_mfma_f32_16x16x32_f16(aP, bv0, ca0, 0, 0, 0);
    ca1 = __builtin_amdgcn_mfma_f32_16x16x32_f16(aP, bv1, ca1, 0, 0, 0);
    ca2 = __builtin_amdgcn_mfma_f32_16x16x32_f16(aP, bv2, ca2, 0, 0, 0);
    ca3 = __builtin_amdgcn_mfma_f32_16x16x32_f16(aP, bv3, ca3, 0, 0, 0);
  }
  float* cw = ctx + ((long)bh * NN + q0) * DK;
#pragma unroll
  for (int j = 0; j < 4; ++j) {
    cw[(4 * g + j) * DK + 0  + s] = ca0[j];
    cw[(4 * g + j) * DK + 16 + s] = ca1[j];
    cw[(4 * g + j) * DK + 32 + s] = ca2[j];
    cw[(4 * g + j) * DK + 48 + s] = ca3[j];
  }
}

extern "C" void kernel_launch(void* const* d_in, const int* in_sizes, int n_in,
                              void* d_out, int out_size, void* d_ws, size_t ws_size,
                              hipStream_t stream) {
  const float* Q = (const float*)d_in[0];
  const float* K = (const float*)d_in[1];
  const float* V = (const float*)d_in[2];
  const void* mask = d_in[3];
  const float* edge = (const float*)d_in[4];
  const float* W1 = (const float*)d_in[5];
  const float* b1 = (const float*)d_in[6];
  const float* W2 = (const float*)d_in[7];
  const float* b2 = (const float*)d_in[8];
  float* ctx = (float*)d_out;
  float* attn = ctx + QSZ;                  // outputs: context then attn
  char* ws = (char*)d_ws;
  if (ws_size < WS_NEED) return;
  _Float16* Qh = (_Float16*)(ws + OFF_QH);
  _Float16* Kh = (_Float16*)(ws + OFF_KH);
  _Float16* Vt = (_Float16*)(ws + OFF_VT);
  float* biasM = (float*)(ws + OFF_BIAS);
  int* flag = (int*)(ws + OFF_FLAG);

  (void)hipMemsetAsync(flag, 0, 4, stream);
  k_detect<<<1, 256, 0, stream>>>((const unsigned char*)mask, flag);
  k_prep_qk<<<8192, 256, 0, stream>>>(Q, K, Qh, Kh);
  k_prep_vt<<<1024, 256, 0, stream>>>(V, Vt);
  k_bias<<<8192, 256, 0, stream>>>(edge, mask, W1, b1, W2, b2, flag, biasM);
  k_attn<<<1024, 256, 0, stream>>>(Qh, Kh, Vt, biasM, ctx, attn);
}

// Round 5
// 419.269 us; speedup vs baseline: 1.4903x; 1.3051x over previous
//
#include <hip/hip_runtime.h>

// Problem constants
constexpr int NB = 8, NH = 8, NN = 1024, DK = 64, ED = 16;
constexpr long QSZ = (long)NB * NH * NN * DK;       // 4,194,304

typedef _Float16 h8 __attribute__((ext_vector_type(8)));
typedef _Float16 h4 __attribute__((ext_vector_type(4)));
typedef _Float16 h2 __attribute__((ext_vector_type(2)));
typedef float f4 __attribute__((ext_vector_type(4)));
typedef float fv16 __attribute__((ext_vector_type(16)));

// ws layout (bytes)
constexpr size_t OFF_QH = 0;                         // 8 MiB fp16 (pre-scaled by 0.125*log2e)
constexpr size_t OFF_KH = 8388608;                   // 8 MiB fp16
constexpr size_t OFF_VT = 16777216;                  // 8 MiB fp16 (transposed [bh][d][k])
constexpr size_t OFF_BIAS = 25165824;                // 32 MiB fp32 (bias*log2e, masked=-1e9)
constexpr size_t OFF_FLAG = 58720256;                // 4 B
constexpr size_t WS_NEED = OFF_FLAG + 4;

constexpr float LG2E = 1.4426950408889634f;          // log2(e)
constexpr float C2 = 2.8853900817779268f;            // 2*log2(e)
constexpr float QS = 0.125f * LG2E;                  // fold 1/sqrt(dk) and log2e into Q

static __device__ __forceinline__ float fexp2(float x) {
  float r; asm("v_exp_f32 %0, %1" : "=v"(r) : "v"(x)); return r;
}
static __device__ __forceinline__ float frcp(float x) {
  float r; asm("v_rcp_f32 %0, %1" : "=v"(r) : "v"(x)); return r;
}
static __device__ __forceinline__ h2 pkrtz(float a, float b) {
  return __builtin_bit_cast(h2, __builtin_amdgcn_cvt_pkrtz(a, b));
}

// ---------- prep: Q (x 0.125*log2e) and K -> fp16, same layout ----------
__global__ __launch_bounds__(256) void k_prep_qk(
    const float* __restrict__ Q, const float* __restrict__ K,
    _Float16* __restrict__ Qh, _Float16* __restrict__ Kh) {
  int i = blockIdx.x * 256 + threadIdx.x;
  const int n4 = (int)(QSZ / 4);
  if (i < n4) {
    float4 v = reinterpret_cast<const float4*>(Q)[i];
    h4 o; o[0] = (_Float16)(v.x * QS); o[1] = (_Float16)(v.y * QS);
          o[2] = (_Float16)(v.z * QS); o[3] = (_Float16)(v.w * QS);
    reinterpret_cast<h4*>(Qh)[i] = o;
  } else {
    int j = i - n4;
    float4 v = reinterpret_cast<const float4*>(K)[j];
    h4 o; o[0] = (_Float16)v.x; o[1] = (_Float16)v.y;
          o[2] = (_Float16)v.z; o[3] = (_Float16)v.w;
    reinterpret_cast<h4*>(Kh)[j] = o;
  }
}

// ---------- prep: V [bh][k][d] fp32 -> Vt [bh][d][k] fp16 ----------
__global__ __launch_bounds__(256) void k_prep_vt(
    const float* __restrict__ V, _Float16* __restrict__ Vt) {
  int wid = (blockIdx.x * 256 + threadIdx.x) >> 6;   // 4096 waves
  int lane = threadIdx.x & 63;
  int bh = wid >> 6;
  int k0 = (wid & 63) << 4;
  const float* Vb = V + (long)bh * NN * DK;
  _Float16* Vo = Vt + (long)bh * DK * NN + (long)lane * NN + k0;
  h8 p0, p1;
#pragma unroll
  for (int i = 0; i < 16; ++i) {
    float v = Vb[(long)(k0 + i) * DK + lane];
    if (i < 8) p0[i] = (_Float16)v; else p1[i - 8] = (_Float16)v;
  }
  *reinterpret_cast<h8*>(Vo) = p0;
  *reinterpret_cast<h8*>(Vo + 8) = p1;
}

// ---------- detect mask element width (bool bytes vs int32) ----------
__global__ void k_detect(const unsigned char* __restrict__ m, int* __restrict__ flag) {
  int t = threadIdx.x;
  int any = 0;
  for (int i = t; i < 4096; i += 256)
    if ((i & 3) && m[i]) any = 1;          // int32 0/1 never has nonzero at %4!=0
  unsigned long long b = __ballot(any);
  if ((t & 63) == 0 && b) atomicOr(flag, 1);
}

// ---------- edge-bias MLP + mask fold: biasM[b][q][k] = bias*log2e (or -1e9) ----------
// 32x32x16 MFMA, K = ED = 16 exactly (no padding, no idle lanes):
//   A = W1^T*C2 (d rows), B = edge chunk (k cols), C-in = b1*C2.
//   D[d][k]: col k = lane&31, row d = 32t + (reg&3) + 8*(reg>>2) + 4*(lane>>5).
// tanh(h) = 1 - 2*rcp(1+exp2(C2*h)); bias = sumW2 + b2 - 2*sum W2[d]*r_d.
// Chunks processed in pairs: lane half h stores chunk h -> 256B coalesced store.
__global__ __launch_bounds__(256) void k_bias(
    const float* __restrict__ edge, const void* __restrict__ maskp,
    const float* __restrict__ W1, const float* __restrict__ b1,
    const float* __restrict__ W2, const float* __restrict__ b2,
    const int* __restrict__ flag, float* __restrict__ biasM) {
  int bq = blockIdx.x;
  int w = threadIdx.x >> 6, l = threadIdx.x & 63;
  int h = l >> 5, c31 = l & 31;
  bool isbool = (*flag != 0);
  // A-frags: lane holds A_t[row=c31][e=8h+j] = W1[8h+j][32t+c31]*C2
  h8 aw0, aw1;
#pragma unroll
  for (int j = 0; j < 8; ++j) {
    aw0[j] = (_Float16)(W1[(8 * h + j) * 64 + 0  + c31] * C2);
    aw1[j] = (_Float16)(W1[(8 * h + j) * 64 + 32 + c31] * C2);
  }
  // C-in (b1*C2) and W2 in D layout: d = 32t + (reg&3) + 8*(reg>>2) + 4*h
  fv16 cb0, cb1;
  float w20[16], w21[16];
  float sw = 0.f;
#pragma unroll
  for (int r = 0; r < 16; ++r) {
    int dr = (r & 3) + 8 * (r >> 2) + 4 * h;
    cb0[r] = b1[dr] * C2;      w20[r] = W2[dr];
    cb1[r] = b1[32 + dr] * C2; w21[r] = W2[32 + dr];
    sw += w20[r] + w21[r];
  }
  sw += __shfl_xor(sw, 32, 64);
  float base = (sw + b2[0]) * LG2E;

  const float* erow = edge + (long)bq * NN * ED;
  const float4* erow4 = reinterpret_cast<const float4*>(erow);
  float* orow = biasM + (long)bq * NN;
  const int* mrowi = (const int*)maskp + (long)bq * NN;
  const unsigned char* mrowb = (const unsigned char*)maskp + (long)bq * NN;

  int kbase = w * 256;
  // current pair regs: chunk0 (e0a,e0b), chunk1 (e1a,e1b); lane reads
  // edge[(k0 + c31)*16 + 8h .. +8) = float4 idx (k0+c31)*4 + 2h, +1
  float4 e0a = erow4[(kbase + c31) * 4 + 2 * h];
  float4 e0b = erow4[(kbase + c31) * 4 + 2 * h + 1];
  float4 e1a = erow4[(kbase + 32 + c31) * 4 + 2 * h];
  float4 e1b = erow4[(kbase + 32 + c31) * 4 + 2 * h + 1];
#pragma unroll
  for (int p = 0; p < 4; ++p) {
    float4 n0a, n0b, n1a, n1b;
    if (p < 3) {
      int nb = kbase + 64;
      n0a = erow4[(nb + c31) * 4 + 2 * h];
      n0b = erow4[(nb + c31) * 4 + 2 * h + 1];
      n1a = erow4[(nb + 32 + c31) * 4 + 2 * h];
      n1b = erow4[(nb + 32 + c31) * 4 + 2 * h + 1];
    }
    union { h8 v; h2 q[4]; } u0, u1;
    u0.q[0] = pkrtz(e0a.x, e0a.y); u0.q[1] = pkrtz(e0a.z, e0a.w);
    u0.q[2] = pkrtz(e0b.x, e0b.y); u0.q[3] = pkrtz(e0b.z, e0b.w);
    u1.q[0] = pkrtz(e1a.x, e1a.y); u1.q[1] = pkrtz(e1a.z, e1a.w);
    u1.q[2] = pkrtz(e1b.x, e1b.y); u1.q[3] = pkrtz(e1b.z, e1b.w);
    fv16 hA0 = __builtin_amdgcn_mfma_f32_32x32x16_f16(aw0, u0.v, cb0, 0, 0, 0);
    fv16 hB0 = __builtin_amdgcn_mfma_f32_32x32x16_f16(aw1, u0.v, cb1, 0, 0, 0);
    fv16 hA1 = __builtin_amdgcn_mfma_f32_32x32x16_f16(aw0, u1.v, cb0, 0, 0, 0);
    fv16 hB1 = __builtin_amdgcn_mfma_f32_32x32x16_f16(aw1, u1.v, cb1, 0, 0, 0);
    // 4-way split accumulators: 16-way ILP on the trans pipe
    float a00 = 0.f, a01 = 0.f, a02 = 0.f, a03 = 0.f;
    float a10 = 0.f, a11 = 0.f, a12 = 0.f, a13 = 0.f;
#pragma unroll
    for (int r = 0; r < 16; r += 4) {
      a00 = fmaf(w20[r + 0], frcp(fexp2(hA0[r + 0]) + 1.f), a00);
      a01 = fmaf(w20[r + 1], frcp(fexp2(hA0[r + 1]) + 1.f), a01);
      a02 = fmaf(w20[r + 2], frcp(fexp2(hA0[r + 2]) + 1.f), a02);
      a03 = fmaf(w20[r + 3], frcp(fexp2(hA0[r + 3]) + 1.f), a03);
      a00 = fmaf(w21[r + 0], frcp(fexp2(hB0[r + 0]) + 1.f), a00);
      a01 = fmaf(w21[r + 1], frcp(fexp2(hB0[r + 1]) + 1.f), a01);
      a02 = fmaf(w21[r + 2], frcp(fexp2(hB0[r + 2]) + 1.f), a02);
      a03 = fmaf(w21[r + 3], frcp(fexp2(hB0[r + 3]) + 1.f), a03);
      a10 = fmaf(w20[r + 0], frcp(fexp2(hA1[r + 0]) + 1.f), a10);
      a11 = fmaf(w20[r + 1], frcp(fexp2(hA1[r + 1]) + 1.f), a11);
      a12 = fmaf(w20[r + 2], frcp(fexp2(hA1[r + 2]) + 1.f), a12);
      a13 = fmaf(w20[r + 3], frcp(fexp2(hA1[r + 3]) + 1.f), a13);
      a10 = fmaf(w21[r + 0], frcp(fexp2(hB1[r + 0]) + 1.f), a10);
      a11 = fmaf(w21[r + 1], frcp(fexp2(hB1[r + 1]) + 1.f), a11);
      a12 = fmaf(w21[r + 2], frcp(fexp2(hB1[r + 2]) + 1.f), a12);
      a13 = fmaf(w21[r + 3], frcp(fexp2(hB1[r + 3]) + 1.f), a13);
    }
    float p0 = (a00 + a01) + (a02 + a03);
    float p1 = (a10 + a11) + (a12 + a13);
    p0 += __shfl_xor(p0, 32, 64);
    p1 += __shfl_xor(p1, 32, 64);
    float part = h ? p1 : p0;
    int idx = kbase + 32 * h + c31;          // 64 lanes -> 64 consecutive floats
    int m = isbool ? (int)mrowb[idx] : mrowi[idx];
    orow[idx] = m ? -1e9f : fmaf(-C2, part, base);
    e0a = n0a; e0b = n0b; e1a = n1a; e1b = n1b;
    kbase += 64;
  }
}

// ---------- fused attention: S' = Qh*Kh + biasM (base-2 domain) ; softmax ; PV ----------
__global__ __launch_bounds__(256) void k_attn(
    const _Float16* __restrict__ Qh, const _Float16* __restrict__ Kh,
    const _Float16* __restrict__ Vt, const float* __restrict__ biasM,
    float* __restrict__ ctx, float* __restrict__ attn) {
  int bid = blockIdx.x;
  int bh = bid >> 4, qb = bid & 15;
  int b = bh >> 3;
  int w = threadIdx.x >> 6, l = threadIdx.x & 63;
  int g = l >> 4, s = l & 15;
  int q0 = qb * 64 + w * 16;
  const _Float16* Qw = Qh + ((long)bh * NN + q0) * DK;
  const _Float16* Kb = Kh + (long)bh * NN * DK;
  const _Float16* Vb = Vt + (long)bh * DK * NN;
  const float* bias0 = biasM + (long)b * NN * NN + (long)q0 * NN;
  h8 aQ0 = *reinterpret_cast<const h8*>(Qw + s * DK + 8 * g);
  h8 aQ1 = *reinterpret_cast<const h8*>(Qw + s * DK + 32 + 8 * g);
  const float* bl0 = bias0 + (long)(4 * g + 0) * NN + s;
  const float* bl1 = bias0 + (long)(4 * g + 1) * NN + s;
  const float* bl2 = bias0 + (long)(4 * g + 2) * NN + s;
  const float* bl3 = bias0 + (long)(4 * g + 3) * NN + s;

  // pass 1: row sums of exp2(S')
  float ls0 = 0.f, ls1 = 0.f, ls2 = 0.f, ls3 = 0.f;
  for (int c0 = 0; c0 < NN; c0 += 32) {
#pragma unroll
    for (int ct = 0; ct < 2; ++ct) {
      int kv = c0 + ct * 16;
      const _Float16* kp = Kb + (long)(kv + s) * DK + 8 * g;
      h8 bk0 = *reinterpret_cast<const h8*>(kp);
      h8 bk1 = *reinterpret_cast<const h8*>(kp + 32);
      f4 acc = {0.f, 0.f, 0.f, 0.f};
      acc = __builtin_amdgcn_mfma_f32_16x16x32_f16(aQ0, bk0, acc, 0, 0, 0);
      acc = __builtin_amdgcn_mfma_f32_16x16x32_f16(aQ1, bk1, acc, 0, 0, 0);
      ls0 += fexp2(acc[0] + bl0[kv]);
      ls1 += fexp2(acc[1] + bl1[kv]);
      ls2 += fexp2(acc[2] + bl2[kv]);
      ls3 += fexp2(acc[3] + bl3[kv]);
    }
  }
#pragma unroll
  for (int m = 1; m < 16; m <<= 1) {
    ls0 += __shfl_xor(ls0, m, 64);
    ls1 += __shfl_xor(ls1, m, 64);
    ls2 += __shfl_xor(ls2, m, 64);
    ls3 += __shfl_xor(ls3, m, 64);
  }
  float iv0 = frcp(ls0), iv1 = frcp(ls1), iv2 = frcp(ls2), iv3 = frcp(ls3);

  // pass 2: recompute S', write attn, accumulate PV
  __shared__ _Float16 plds[4][16][40];   // per-wave P chunk [16 q][32 kv], pitch 40
  f4 ca0 = {0.f,0.f,0.f,0.f}, ca1 = {0.f,0.f,0.f,0.f};
  f4 ca2 = {0.f,0.f,0.f,0.f}, ca3 = {0.f,0.f,0.f,0.f};
  float* attnw = attn + ((long)bh * NN + q0) * NN;
  for (int c0 = 0; c0 < NN; c0 += 32) {
#pragma unroll
    for (int ct = 0; ct < 2; ++ct) {
      int kv = c0 + ct * 16;
      const _Float16* kp = Kb + (long)(kv + s) * DK + 8 * g;
      h8 bk0 = *reinterpret_cast<const h8*>(kp);
      h8 bk1 = *reinterpret_cast<const h8*>(kp + 32);
      f4 acc = {0.f, 0.f, 0.f, 0.f};
      acc = __builtin_amdgcn_mfma_f32_16x16x32_f16(aQ0, bk0, acc, 0, 0, 0);
      acc = __builtin_amdgcn_mfma_f32_16x16x32_f16(aQ1, bk1, acc, 0, 0, 0);
      float p0 = fexp2(acc[0] + bl0[kv]) * iv0;
      float p1 = fexp2(acc[1] + bl1[kv]) * iv1;
      float p2 = fexp2(acc[2] + bl2[kv]) * iv2;
      float p3 = fexp2(acc[3] + bl3[kv]) * iv3;
      attnw[(4 * g + 0) * NN + kv + s] = p0;
      attnw[(4 * g + 1) * NN + kv + s] = p1;
      attnw[(4 * g + 2) * NN + kv + s] = p2;
      attnw[(4 * g + 3) * NN + kv + s] = p3;
      plds[w][4 * g + 0][ct * 16 + s] = (_Float16)p0;
      plds[w][4 * g + 1][ct * 16 + s] = (_Float16)p1;
      plds[w][4 * g + 2][ct * 16 + s] = (_Float16)p2;
      plds[w][4 * g + 3][ct * 16 + s] = (_Float16)p3;
    }
    h8 aP = *reinterpret_cast<const h8*>(&plds[w][s][8 * g]);
    const _Float16* vp = Vb + (long)s * NN + c0 + 8 * g;
    h8 bv0 = *reinterpret_cast<const h8*>(vp);
    h8 bv1 = *reinterpret_cast<const h8*>(vp + 16 * NN);
    h8 bv2 = *reinterpret_cast<const h8*>(vp + 32 * NN);
    h8 bv3 = *reinterpret_cast<const h8*>(vp + 48 * NN);
    ca0 = __builtin_amdgcn_mfma_f32_16x16x32_f16(aP, bv0, ca0, 0, 0, 0);
    ca1 = __builtin_amdgcn_mfma_f32_16x16x32_f16(aP, bv1, ca1, 0, 0, 0);
    ca2 = __builtin_amdgcn_mfma_f32_16x16x32_f16(aP, bv2, ca2, 0, 0, 0);
    ca3 = __builtin_amdgcn_mfma_f32_16x16x32_f16(aP, bv3, ca3, 0, 0, 0);
  }
  float* cw = ctx + ((long)bh * NN + q0) * DK;
#pragma unroll
  for (int j = 0; j < 4; ++j) {
    cw[(4 * g + j) * DK + 0  + s] = ca0[j];
    cw[(4 * g + j) * DK + 16 + s] = ca1[j];
    cw[(4 * g + j) * DK + 32 + s] = ca2[j];
    cw[(4 * g + j) * DK + 48 + s] = ca3[j];
  }
}

extern "C" void kernel_launch(void* const* d_in, const int* in_sizes, int n_in,
                              void* d_out, int out_size, void* d_ws, size_t ws_size,
                              hipStream_t stream) {
  const float* Q = (const float*)d_in[0];
  const float* K = (const float*)d_in[1];
  const float* V = (const float*)d_in[2];
  const void* mask = d_in[3];
  const float* edge = (const float*)d_in[4];
  const float* W1 = (const float*)d_in[5];
  const float* b1 = (const float*)d_in[6];
  const float* W2 = (const float*)d_in[7];
  const float* b2 = (const float*)d_in[8];
  float* ctx = (float*)d_out;
  float* attn = ctx + QSZ;                  // outputs: context then attn
  char* ws = (char*)d_ws;
  if (ws_size < WS_NEED) return;
  _Float16* Qh = (_Float16*)(ws + OFF_QH);
  _Float16* Kh = (_Float16*)(ws + OFF_KH);
  _Float16* Vt = (_Float16*)(ws + OFF_VT);
  float* biasM = (float*)(ws + OFF_BIAS);
  int* flag = (int*)(ws + OFF_FLAG);

  (void)hipMemsetAsync(flag, 0, 4, stream);
  k_detect<<<1, 256, 0, stream>>>((const unsigned char*)mask, flag);
  k_prep_qk<<<8192, 256, 0, stream>>>(Q, K, Qh, Kh);
  k_prep_vt<<<1024, 256, 0, stream>>>(V, Vt);
  k_bias<<<8192, 256, 0, stream>>>(edge, mask, W1, b1, W2, b2, flag, biasM);
  k_attn<<<1024, 256, 0, stream>>>(Qh, Kh, Vt, biasM, ctx, attn);
}